// Round 6
// baseline (201.584 us; speedup 1.0000x reference)
//
#include <hip/hip_runtime.h>
#include <hip/hip_bf16.h>

// Problem constants
#define BATCH   256
#define NP      196
#define HIDDEN  1024
#define ATT     512
#define M_TOTAL (BATCH * NP)   // 50176 rows
#define BM 256
#define BN 256
#define BK 64
#define NB_TILES (ATT / BN)       // 2
#define MT_TILES (M_TOTAL / BM)   // 196
#define KSTEPS   (HIDDEN / BK)    // 16

typedef __attribute__((ext_vector_type(8))) short bf16x8v;  // 8 bf16 = 4 VGPR
typedef __attribute__((ext_vector_type(4))) float f32x4;

// f32 -> bf16 RNE (used only in K0 prep, cold path)
__device__ inline unsigned short f2bf(float x) {
    unsigned int u = __float_as_uint(x);
    u += 0x7fffu + ((u >> 16) & 1u);
    return (unsigned short)(u >> 16);
}

// packed f32 pair -> 2x bf16 in one uint via v_cvt_pk_bf16_f32
__device__ __forceinline__ unsigned int pk2bf(float lo, float hi) {
    unsigned int r;
    asm("v_cvt_pk_bf16_f32 %0, %1, %2" : "=v"(r) : "v"(lo), "v"(hi));
    return r;
}

__device__ inline float fast_tanh(float x) {
    float e = __expf(2.0f * x);
    return 1.0f - 2.0f / (e + 1.0f);
}

// async global->LDS, 16 bytes per lane. LDS dest must be wave-uniform base + lane*16.
__device__ __forceinline__ void glds16(const void* gsrc, void* ldst) {
    __builtin_amdgcn_global_load_lds(
        (const __attribute__((address_space(1))) unsigned int*)gsrc,
        (__attribute__((address_space(3))) unsigned int*)ldst,
        16, 0, 0);
}

// ---------------------------------------------------------------------------
// K0: W_cnn (f32 [1024][512]) -> bf16 tiled+XOR-swizzled for K2's B LDS image.
// Image per (nb, ks): 32 KB, byte = col*128 + cp*16; the 16B slot (col, cp)
// holds k-chunk c = cp ^ (col&7) (8 consecutive k), k = ks*64 + c*8 + j.
// glds copies the image linearly; the read applies the same XOR (rule #21).
// ---------------------------------------------------------------------------
__global__ void k0_arrange(const float* __restrict__ Wc, unsigned short* __restrict__ Wt) {
    int g = blockIdx.x * 256 + threadIdx.x;   // 65536 slots of 8 bf16
    int nb  = g >> 15;
    int ks  = (g >> 11) & 15;
    int col = (g >> 3) & 255;
    int cp  = g & 7;
    int c   = cp ^ (col & 7);
    int kb  = ks * 64 + c * 8;
    int colg = nb * 256 + col;
    unsigned short v[8];
#pragma unroll
    for (int j = 0; j < 8; ++j) v[j] = f2bf(Wc[(size_t)(kb + j) * ATT + colg]);
    uint4 pk;
    pk.x = (unsigned int)v[0] | ((unsigned int)v[1] << 16);
    pk.y = (unsigned int)v[2] | ((unsigned int)v[3] << 16);
    pk.z = (unsigned int)v[4] | ((unsigned int)v[5] << 16);
    pk.w = (unsigned int)v[6] | ((unsigned int)v[7] << 16);
    *(uint4*)(Wt + (size_t)g * 8) = pk;
}

// ---------------------------------------------------------------------------
// K1: dec_out = decoder_out @ W_dec ; stw = st @ W_sen   (f32)
// ---------------------------------------------------------------------------
__global__ void k1_small(const float* __restrict__ dec_in, const float* __restrict__ st,
                         const float* __restrict__ Wdec,  const float* __restrict__ Wsen,
                         float* __restrict__ dec_out, float* __restrict__ stw) {
    const float* X = blockIdx.z ? st   : dec_in;
    const float* W = blockIdx.z ? Wsen : Wdec;
    float*       O = blockIdx.z ? stw  : dec_out;
    int ci = threadIdx.x & 31;
    int c0 = blockIdx.x * 128 + ci * 4;
    int b  = blockIdx.y * 8 + (threadIdx.x >> 5);
    const float* x = X + (size_t)b * HIDDEN;
    float4 acc = {0.f, 0.f, 0.f, 0.f};
    for (int k = 0; k < HIDDEN; k += 4) {
#pragma unroll
        for (int kk = 0; kk < 4; ++kk) {
            float4 w = *(const float4*)(W + (size_t)(k + kk) * ATT + c0);
            float a = x[k + kk];
            acc.x += a * w.x; acc.y += a * w.y; acc.z += a * w.z; acc.w += a * w.w;
        }
    }
    *(float4*)(O + (size_t)b * ATT + c0) = acc;
}

// ---------------------------------------------------------------------------
// K2: fused  zt_part[nb][r] = sum_{cols of nb} tanh((A@Wc)[r,a]+dec)*Watt[a]
// 256x256 tile, BK=64, 512 thr / 8 waves (2M x 4N), per-wave 128x64 out
// (acc[8][4], 128 AGPR). Two-phase dbuf: A reg-staged (T14 split: loads at
// iter top, cvt+ds_write after compute), B via 4x glds16 from pre-swizzled Wt.
// One vmcnt(0)+lgkmcnt(0)+s_barrier per K-step; both operands get a full
// compute phase (~2000 cy) of latency coverage. All LDS access XOR-swizzled
// (chunk ^ (row&7)) -> conflict-free ds_read_b128 / ds_write_b64.
// ---------------------------------------------------------------------------
__global__ void __launch_bounds__(512, 2)
k2_fused_gemm(const float* __restrict__ A, const unsigned short* __restrict__ Wt,
              const float* __restrict__ dec, const float* __restrict__ Watt,
              float* __restrict__ ztp) {
    // [Abuf0 32K][Abuf1 32K][Bbuf0 32K][Bbuf1 32K]; row/col-major 128 B rows.
    __shared__ __align__(16) char lds[131072];
    __shared__ float zred[1024];

    const int tid = threadIdx.x;
    const int w  = tid >> 6;
    const int l  = tid & 63;
    const int lg = l >> 4, ll = l & 15;
    const int wr = w >> 2, wc = w & 3;       // wave grid 2 (rows) x 4 (cols)

    // XCD-bijective swizzle: 392 blocks = 8 XCDs x 49; consecutive swz pairs
    // share an A strip (nb 0/1 of the same mt) -> L2 reuse within the XCD.
    const int bid = (int)blockIdx.x;
    const int swz = (bid & 7) * 49 + (bid >> 3);
    const int mt = swz >> 1, nb = swz & 1;
    const int r0 = mt * BM;
    const int c0 = nb * BN;

    char* Abuf0 = lds;
    char* Abuf1 = lds + 32768;
    char* Bbuf0 = lds + 65536;
    char* Bbuf1 = lds + 98304;

    f32x4 acc[8][4];
#pragma unroll
    for (int m = 0; m < 8; ++m)
#pragma unroll
        for (int n = 0; n < 4; ++n) acc[m][n] = (f32x4){0.f, 0.f, 0.f, 0.f};

    // ---- A staging geometry -------------------------------------------------
    // Per instr j (j=0..7): row = (tid>>4) + 32*j, 16B slot k4 = tid&15
    // (4 consecutive f32 at k = k4*4 within the 64-wide K-step).
    // Global: per-instr the wave reads 4 rows x 256 B contiguous (coalesced).
    // LDS: byte = row*128 + ((c ^ (row&7))<<4) + half*8, c = k4>>1, half = k4&1.
    // row&7 is per-thread uniform ((tid>>4)&7), so the swizzle offset is constant.
    const int arow_b = tid >> 4;             // 0..31
    const int k4 = tid & 15;
    const float* asrc = A + (size_t)(r0 + arow_b) * HIDDEN + k4 * 4;
    const int aw_off = ((((k4 >> 1) ^ (arow_b & 7)) << 4) | ((k4 & 1) << 3));

    // B: linear image copy, 4 x 8KB spans per K-step.
    const char* bsrc = (const char*)Wt + (size_t)nb * (KSTEPS * 32768) + tid * 16;

    float4 av[8];

#define ALOAD(t) do {                                                          \
    _Pragma("unroll")                                                          \
    for (int j = 0; j < 8; ++j)                                                \
        av[j] = *(const float4*)(asrc + (size_t)j * 32 * HIDDEN + (t) * 64);   \
} while (0)

#define BGLDS(t, Bb) do {                                                      \
    _Pragma("unroll")                                                          \
    for (int q = 0; q < 4; ++q)                                                \
        glds16(bsrc + (size_t)(t) * 32768 + q * 8192, (Bb) + q * 8192 + tid * 16); \
} while (0)

#define AWRITE(Ab) do {                                                        \
    _Pragma("unroll")                                                          \
    for (int j = 0; j < 8; ++j) {                                              \
        int row = arow_b + 32 * j;                                             \
        uint2 u;                                                               \
        u.x = pk2bf(av[j].x, av[j].y);                                         \
        u.y = pk2bf(av[j].z, av[j].w);                                         \
        *(uint2*)((Ab) + row * 128 + aw_off) = u;                              \
    }                                                                          \
} while (0)

#define COMPUTE(Ab, Bb) do {                                                   \
    _Pragma("unroll")                                                          \
    for (int kk = 0; kk < 2; ++kk) {                                           \
        bf16x8v bfr[4];                                                        \
        _Pragma("unroll")                                                      \
        for (int n = 0; n < 4; ++n) {                                          \
            int coll = wc * 64 + n * 16 + ll;                                  \
            bfr[n] = *(const bf16x8v*)((Bb) + coll * 128 +                     \
                                       (((kk * 4 + lg) ^ (ll & 7)) << 4));     \
        }                                                                      \
        _Pragma("unroll")                                                      \
        for (int m = 0; m < 8; ++m) {                                          \
            int rowl = wr * 128 + m * 16 + ll;                                 \
            bf16x8v af = *(const bf16x8v*)((Ab) + rowl * 128 +                 \
                                           (((kk * 4 + lg) ^ (ll & 7)) << 4)); \
            _Pragma("unroll")                                                  \
            for (int n = 0; n < 4; ++n)                                        \
                acc[m][n] = __builtin_amdgcn_mfma_f32_16x16x32_bf16(           \
                    af, bfr[n], acc[m][n], 0, 0, 0);                           \
        }                                                                      \
    }                                                                          \
} while (0)

#define SYNC do {                                                              \
    asm volatile("s_waitcnt vmcnt(0) lgkmcnt(0)" ::: "memory");                \
    __builtin_amdgcn_s_barrier();                                              \
} while (0)

    // ---- Prologue: stage tile 0 ----
    ALOAD(0);
    BGLDS(0, Bbuf0);
    AWRITE(Abuf0);          // compiler auto-waits the A loads (vmcnt(4))
    SYNC;

    // ---- Main loop: even tiles in buf0, odd in buf1 (compile-time bufs) ----
    for (int tb = 0; tb < 14; tb += 2) {
        ALOAD(tb + 1);
        BGLDS(tb + 1, Bbuf1);
        COMPUTE(Abuf0, Bbuf0);   // tile tb
        AWRITE(Abuf1);           // tile tb+1
        SYNC;
        ALOAD(tb + 2);
        BGLDS(tb + 2, Bbuf0);
        COMPUTE(Abuf1, Bbuf1);   // tile tb+1
        AWRITE(Abuf0);           // tile tb+2
        SYNC;
    }
    // tile 14: stage 15, compute 14
    ALOAD(15);
    BGLDS(15, Bbuf1);
    COMPUTE(Abuf0, Bbuf0);
    AWRITE(Abuf1);
    SYNC;
    // tile 15: drain
    COMPUTE(Abuf1, Bbuf1);

#undef ALOAD
#undef BGLDS
#undef AWRITE
#undef COMPUTE
#undef SYNC

    // ---- Epilogue: tanh + dec add + Watt dot; reduce over the wave's 64 cols.
    // C frag layout: row = lg*4 + j, col = ll (m89-verified).
    const int clocal = wc * 64 + ll;
    float watt[4];
#pragma unroll
    for (int n = 0; n < 4; ++n) watt[n] = Watt[c0 + clocal + n * 16];

#pragma unroll
    for (int m = 0; m < 8; ++m) {
#pragma unroll
        for (int j = 0; j < 4; ++j) {
            int rl = wr * 128 + m * 16 + lg * 4 + j;
            int rowg = r0 + rl;
            int b = rowg / NP;
            const float* db = dec + (size_t)b * ATT + c0;
            float s = 0.f;
#pragma unroll
            for (int n = 0; n < 4; ++n)
                s += fast_tanh(acc[m][n][j] + db[clocal + n * 16]) * watt[n];
            s += __shfl_xor(s, 1);
            s += __shfl_xor(s, 2);
            s += __shfl_xor(s, 4);
            s += __shfl_xor(s, 8);
            if (ll == 0) zred[rl * 4 + wc] = s;
        }
    }
    __syncthreads();
    if (tid < 256) {
        float t = zred[tid * 4] + zred[tid * 4 + 1] + zred[tid * 4 + 2] + zred[tid * 4 + 3];
        ztp[(size_t)nb * M_TOTAL + r0 + tid] = t;
    }
}

// ---------------------------------------------------------------------------
// K3: per-b: out = tanh(dec+stw)@Watt ; alpha = softmax(zt) ; beta.
// zt = sum of 2 N-block partials.
// ---------------------------------------------------------------------------
__global__ void k3_softmax(const float* __restrict__ dec, const float* __restrict__ stw,
                           const float* __restrict__ Watt, const float* __restrict__ ztp,
                           float* __restrict__ out, float* __restrict__ beta_ws) {
    int b = blockIdx.x;
    int t = threadIdx.x;
    __shared__ float red[256];

    float p = 0.f;
#pragma unroll
    for (int c = t; c < ATT; c += 256)
        p += fast_tanh(dec[(size_t)b * ATT + c] + stw[(size_t)b * ATT + c]) * Watt[c];
    red[t] = p;
    __syncthreads();
    for (int s = 128; s > 0; s >>= 1) { if (t < s) red[t] += red[t + s]; __syncthreads(); }
    float outv = red[0];
    __syncthreads();

    float z = -1e30f;
    if (t < NP) z = ztp[b * NP + t] + ztp[M_TOTAL + b * NP + t];
    red[t] = z;
    __syncthreads();
    for (int s = 128; s > 0; s >>= 1) { if (t < s) red[t] = fmaxf(red[t], red[t + s]); __syncthreads(); }
    float m1 = red[0];
    __syncthreads();

    float e = (t < NP) ? __expf(z - m1) : 0.f;
    red[t] = e;
    __syncthreads();
    for (int s = 128; s > 0; s >>= 1) { if (t < s) red[t] += red[t + s]; __syncthreads(); }
    float s1 = red[0];

    if (t < NP) out[b * NP + t] = e / s1;                       // alpha_t

    if (t == 0) {
        float m2 = fmaxf(m1, outv);
        float s2 = s1 * __expf(m1 - m2) + __expf(outv - m2);
        float beta = __expf(outv - m2) / s2;
        out[M_TOTAL + b] = beta;                                 // beta_t
        beta_ws[b] = beta;
    }
}

// ---------------------------------------------------------------------------
// K4: ct partials. grid (4 p-quarters, 256 b), block 256 (thread = 4 h).
// ---------------------------------------------------------------------------
__global__ void k4_ct(const float* __restrict__ spatial, const float* __restrict__ alpha,
                      float* __restrict__ ctp) {
    int q = blockIdx.x;
    int b = blockIdx.y;
    int t = threadIdx.x;
    __shared__ float al[49];
    if (t < 49) al[t] = alpha[b * NP + q * 49 + t];
    __syncthreads();
    const float* sp = spatial + (size_t)b * NP * HIDDEN + (size_t)q * 49 * HIDDEN + t * 4;
    float4 acc = {0.f, 0.f, 0.f, 0.f};
#pragma unroll 7
    for (int p = 0; p < 49; ++p) {
        float4 v = *(const float4*)(sp + (size_t)p * HIDDEN);
        float a = al[p];
        acc.x += a * v.x; acc.y += a * v.y; acc.z += a * v.z; acc.w += a * v.w;
    }
    *(float4*)(ctp + ((size_t)q * BATCH + b) * HIDDEN + t * 4) = acc;
}

// ---------------------------------------------------------------------------
// K5: c_hat = beta*st + (1-beta)*ct  (sums the 4 ct partials)
// ---------------------------------------------------------------------------
__global__ void k5_chat(const float* __restrict__ st, const float* __restrict__ ctp,
                        const float* __restrict__ beta, float* __restrict__ chat) {
    int g = blockIdx.x * 256 + threadIdx.x;
    int b = g >> 8;
    int h0 = (g & 255) * 4;
    float be = beta[b];
    float4 s = *(const float4*)(st + (size_t)b * HIDDEN + h0);
    float4 c = {0.f, 0.f, 0.f, 0.f};
#pragma unroll
    for (int q = 0; q < 4; ++q) {
        float4 v = *(const float4*)(ctp + ((size_t)q * BATCH + b) * HIDDEN + h0);
        c.x += v.x; c.y += v.y; c.z += v.z; c.w += v.w;
    }
    float4 o;
    o.x = be * s.x + (1.f - be) * c.x;
    o.y = be * s.y + (1.f - be) * c.y;
    o.z = be * s.z + (1.f - be) * c.z;
    o.w = be * s.w + (1.f - be) * c.w;
    *(float4*)(chat + (size_t)b * HIDDEN + h0) = o;
}

// ---------------------------------------------------------------------------
extern "C" void kernel_launch(void* const* d_in, const int* in_sizes, int n_in,
                              void* d_out, int out_size, void* d_ws, size_t ws_size,
                              hipStream_t stream) {
    const float* spatial = (const float*)d_in[0];   // (256,196,1024)
    const float* decoder = (const float*)d_in[1];   // (256,1024)
    const float* st      = (const float*)d_in[2];   // (256,1024)
    const float* Wcnn    = (const float*)d_in[3];   // (1024,512)
    const float* Wdec    = (const float*)d_in[4];   // (1024,512)
    const float* Wsen    = (const float*)d_in[5];   // (1024,512)
    const float* Watt    = (const float*)d_in[6];   // (512,1)
    float* out = (float*)d_out;   // alpha[50176] | beta[256] | c_hat[262144]

    char* ws = (char*)d_ws;
    unsigned short* Wt = (unsigned short*)(ws + 0);   // 1 MB tiled+swizzled bf16 W_cnn
    float* ztp  = (float*)(ws + 1048576);             // 2 x 50176 partials
    float* dec  = (float*)(ws + 1449984);             // 256x512
    float* stw  = (float*)(ws + 1974272);             // 256x512
    float* beta = (float*)(ws + 2498560);             // 256
    float* ctp  = (float*)(ws + 2499584);             // 4x256x1024 partials

    k0_arrange<<<256, 256, 0, stream>>>(Wcnn, Wt);
    k1_small<<<dim3(4, 32, 2), 256, 0, stream>>>(decoder, st, Wdec, Wsen, dec, stw);
    k2_fused_gemm<<<MT_TILES * NB_TILES, 512, 0, stream>>>(spatial, Wt, dec, Watt, ztp);
    k3_softmax<<<256, 256, 0, stream>>>(dec, stw, Watt, ztp, out, beta);
    k4_ct<<<dim3(4, 256), 256, 0, stream>>>(spatial, out, ctp);
    k5_chat<<<256, 256, 0, stream>>>(st, ctp, beta, out + M_TOTAL + BATCH);
}

// Round 7
// 199.020 us; speedup vs baseline: 1.0129x; 1.0129x over previous
//
#include <hip/hip_runtime.h>
#include <hip/hip_bf16.h>

// Problem constants
#define BATCH   256
#define NP      196
#define HIDDEN  1024
#define ATT     512
#define M_TOTAL (BATCH * NP)   // 50176 rows
#define BM 128
#define BN 128
#define BK 32
#define NB_TILES (ATT / BN)       // 4
#define MT_TILES (M_TOTAL / BM)   // 392

typedef __attribute__((ext_vector_type(8))) short bf16x8v;  // 8 bf16 = 4 VGPR
typedef __attribute__((ext_vector_type(4))) float f32x4;

// f32 -> bf16 RNE (used only in K0 prep, cold path)
__device__ inline unsigned short f2bf(float x) {
    unsigned int u = __float_as_uint(x);
    u += 0x7fffu + ((u >> 16) & 1u);
    return (unsigned short)(u >> 16);
}

// packed f32 pair -> 2x bf16 in one uint via v_cvt_pk_bf16_f32
__device__ __forceinline__ unsigned int pk2bf(float lo, float hi) {
    unsigned int r;
    asm("v_cvt_pk_bf16_f32 %0, %1, %2" : "=v"(r) : "v"(lo), "v"(hi));
    return r;
}

__device__ inline float fast_tanh(float x) {
    float e = __expf(2.0f * x);
    return 1.0f - 2.0f / (e + 1.0f);
}

// async global->LDS, 16 bytes per lane. LDS dest must be wave-uniform base + lane*16.
__device__ __forceinline__ void glds16(const void* gsrc, void* ldst) {
    __builtin_amdgcn_global_load_lds(
        (const __attribute__((address_space(1))) unsigned int*)gsrc,
        (__attribute__((address_space(3))) unsigned int*)ldst,
        16, 0, 0);
}

// ---------------------------------------------------------------------------
// K0: W_cnn (f32 [1024][512]) -> bf16 tiled+slot-swizzled for K2's B LDS image.
// Wt[nb 4][kt 32][8KB image]; image byte = col*64 + slot*16, col 0..127.
// Slot `slot` holds k-chunk c = slot ^ ((col&7)>>1)  (8 consecutive k).
// glds copies the image linearly; the LDS read applies the same XOR (rule #21).
// ---------------------------------------------------------------------------
__global__ void k0_arrange(const float* __restrict__ Wc, unsigned short* __restrict__ Wt) {
    int g = blockIdx.x * 256 + threadIdx.x;   // 65536 slots of 8 bf16
    int nb   = g >> 14;
    int kt   = (g >> 9) & 31;
    int col  = (g >> 2) & 127;
    int slot = g & 3;
    int c    = slot ^ ((col & 7) >> 1);
    int kb   = kt * 32 + c * 8;
    int colg = nb * 128 + col;
    unsigned short v[8];
#pragma unroll
    for (int j = 0; j < 8; ++j) v[j] = f2bf(Wc[(size_t)(kb + j) * ATT + colg]);
    uint4 pk;
    pk.x = (unsigned int)v[0] | ((unsigned int)v[1] << 16);
    pk.y = (unsigned int)v[2] | ((unsigned int)v[3] << 16);
    pk.z = (unsigned int)v[4] | ((unsigned int)v[5] << 16);
    pk.w = (unsigned int)v[6] | ((unsigned int)v[7] << 16);
    *(uint4*)(Wt + (size_t)g * 8) = pk;
}

// ---------------------------------------------------------------------------
// K1: dec_out = decoder_out @ W_dec ; stw = st @ W_sen   (f32)
// ---------------------------------------------------------------------------
__global__ void k1_small(const float* __restrict__ dec_in, const float* __restrict__ st,
                         const float* __restrict__ Wdec,  const float* __restrict__ Wsen,
                         float* __restrict__ dec_out, float* __restrict__ stw) {
    const float* X = blockIdx.z ? st   : dec_in;
    const float* W = blockIdx.z ? Wsen : Wdec;
    float*       O = blockIdx.z ? stw  : dec_out;
    int ci = threadIdx.x & 31;
    int c0 = blockIdx.x * 128 + ci * 4;
    int b  = blockIdx.y * 8 + (threadIdx.x >> 5);
    const float* x = X + (size_t)b * HIDDEN;
    float4 acc = {0.f, 0.f, 0.f, 0.f};
    for (int k = 0; k < HIDDEN; k += 4) {
#pragma unroll
        for (int kk = 0; kk < 4; ++kk) {
            float4 w = *(const float4*)(W + (size_t)(k + kk) * ATT + c0);
            float a = x[k + kk];
            acc.x += a * w.x; acc.y += a * w.y; acc.z += a * w.z; acc.w += a * w.w;
        }
    }
    *(float4*)(O + (size_t)b * ATT + c0) = acc;
}

// ---------------------------------------------------------------------------
// K2: fused  zt_part[nb][r] = sum_{cols of nb} tanh((A@Wc)[r,a]+dec)*Watt[a]
// m97-faithful geometry: 128x128 tile, 256 thr / 4 waves (2x2), wave 64x64,
// acc[4][4]=64 AGPR, BK=32, grid 1568 (3 blocks/CU -> cross-block TLP covers
// barrier drains, per m97/m114). B via glds16 from pre-swizzled Wt; A
// reg-staged one tile ahead (counted vmcnt(4): the 4 A loads span the
// barrier), cvt at stage time. Double-buffered LDS, ONE barrier per K-step.
// LDS slot-swizzle (chunk ^ ((row&7)>>1)) -> uniform bank access.
// ---------------------------------------------------------------------------
__global__ void __launch_bounds__(256, 3)
k2_fused_gemm(const float* __restrict__ A, const unsigned short* __restrict__ Wt,
              const float* __restrict__ dec, const float* __restrict__ Watt,
              float* __restrict__ ztp) {
    __shared__ __align__(16) char Abuf[2][8192];
    __shared__ __align__(16) char Bbuf[2][8192];
    __shared__ float zred[256];

    const int tid = threadIdx.x;
    const int w  = tid >> 6;
    const int l  = tid & 63;
    const int lg = l >> 4, ll = l & 15;
    const int wr = w >> 1, wc = w & 1;       // wave grid 2x2, wave = 64x64

    // XCD-bijective swizzle: 1568 = 8 XCDs x 196; the 4 nb-blocks of each mt
    // are adjacent within an XCD chunk -> A strip + Wt L2 reuse.
    const int bid = (int)blockIdx.x;
    const int swz = (bid & 7) * 196 + (bid >> 3);
    const int mt = swz >> 2, nb = swz & 3;
    const int r0 = mt * BM;
    const int c0 = nb * BN;

    f32x4 acc[4][4];
#pragma unroll
    for (int m = 0; m < 4; ++m)
#pragma unroll
        for (int n = 0; n < 4; ++n) acc[m][n] = (f32x4){0.f, 0.f, 0.f, 0.f};

    // ---- A staging geometry ----
    // Load instr j (0..3): 16B f32 slot id = j*256 + tid; row = id>>3 = j*32 + (tid>>3),
    // slot s = tid&7 (k = s*4..s*4+3). Per instr a wave reads 8 full rows = 1 KB
    // contiguous (perfect coalescing).
    const float* asrc = A + (size_t)(r0 + (tid >> 3)) * HIDDEN + (tid & 7) * 4;
    // ds_write (b64): byte = row*64 + ((c ^ ((row&7)>>1))<<4) + half*8,
    // c = s>>1 = (tid>>1)&3, half = tid&1, (row&7)>>1 = (tid>>4)&3 (j*32 == 0 mod 8).
    const int aw_off = ((tid >> 3) * 64)
                     + (((((tid >> 1) & 3) ^ ((tid >> 4) & 3))) << 4)
                     + ((tid & 1) * 8);

    // B: linear image copy, 8 KB per K-step, 2 glds per thread.
    const char* bimg = (const char*)Wt + (size_t)nb * (32 * 8192) + tid * 16;

    float4 avA[4], avB[4];

#define ALOADN(t, av) do {                                                     \
    _Pragma("unroll")                                                          \
    for (int j = 0; j < 4; ++j)                                                \
        (av)[j] = *(const float4*)(asrc + (size_t)j * 32 * HIDDEN + (t) * 32); \
} while (0)

#define BGLDS(t, buf) do {                                                     \
    glds16(bimg + (size_t)(t) * 8192,        (buf) + tid * 16);                \
    glds16(bimg + (size_t)(t) * 8192 + 4096, (buf) + 4096 + tid * 16);         \
} while (0)

#define AWRITE(av, buf) do {                                                   \
    _Pragma("unroll")                                                          \
    for (int j = 0; j < 4; ++j) {                                              \
        uint2 u;                                                               \
        u.x = pk2bf((av)[j].x, (av)[j].y);                                     \
        u.y = pk2bf((av)[j].z, (av)[j].w);                                     \
        *(uint2*)((buf) + j * 2048 + aw_off) = u;                              \
    }                                                                          \
} while (0)

#define COMPUTE(Ab, Bb) do {                                                   \
    const int fx = (ll >> 1) & 3;                                              \
    bf16x8v af[4], bfr[4];                                                     \
    _Pragma("unroll")                                                          \
    for (int m = 0; m < 4; ++m)                                                \
        af[m] = *(const bf16x8v*)((Ab) + (wr * 64 + m * 16 + ll) * 64 +        \
                                  ((lg ^ fx) << 4));                           \
    _Pragma("unroll")                                                          \
    for (int n = 0; n < 4; ++n)                                                \
        bfr[n] = *(const bf16x8v*)((Bb) + (wc * 64 + n * 16 + ll) * 64 +       \
                                   ((lg ^ fx) << 4));                          \
    _Pragma("unroll")                                                          \
    for (int m = 0; m < 4; ++m)                                                \
        _Pragma("unroll")                                                      \
        for (int n = 0; n < 4; ++n)                                            \
            acc[m][n] = __builtin_amdgcn_mfma_f32_16x16x32_bf16(               \
                af[m], bfr[n], acc[m][n], 0, 0, 0);                            \
} while (0)

#define WAITC asm volatile("s_waitcnt vmcnt(4) lgkmcnt(0)" ::: "memory")
#define BAR   __builtin_amdgcn_s_barrier()

    // ---- Prologue: tile 0 staged; tile-1 A loads left in flight ----
    BGLDS(0, Bbuf[0]);
    ALOADN(0, avA);
    ALOADN(1, avB);
    AWRITE(avA, Abuf[0]);    // compiler auto-waits avA's loads
    WAITC;                   // B(0) glds done; avB's 4 loads stay in flight
    BAR;

    // ---- Main loop: 30 iters (t=0..29), unroll x2 for compile-time buffers.
    // iter t: stage B(t+1)+issue A(t+2), compute tile t, write A(t+1),
    // counted vmcnt(4) (A(t+2) spans the barrier), ONE barrier.
    for (int tp = 0; tp < 15; ++tp) {
        const int t = tp * 2;
        BGLDS(t + 1, Bbuf[1]);
        ALOADN(t + 2, avA);
        COMPUTE(Abuf[0], Bbuf[0]);
        AWRITE(avB, Abuf[1]);
        WAITC; BAR;
        BGLDS(t + 2, Bbuf[0]);
        ALOADN((t + 3 > 31 ? 31 : t + 3), avB);
        COMPUTE(Abuf[1], Bbuf[1]);
        AWRITE(avA, Abuf[0]);
        WAITC; BAR;
    }
    // t=30: stage tile 31, compute 30
    BGLDS(31, Bbuf[1]);
    COMPUTE(Abuf[0], Bbuf[0]);
    AWRITE(avB, Abuf[1]);
    asm volatile("s_waitcnt vmcnt(0) lgkmcnt(0)" ::: "memory");
    BAR;
    // t=31: drain
    COMPUTE(Abuf[1], Bbuf[1]);

#undef ALOADN
#undef BGLDS
#undef AWRITE
#undef COMPUTE
#undef WAITC
#undef BAR

    // ---- Epilogue: tanh + dec add + Watt dot; reduce the wave's 64 cols/row.
    // C frag layout (m89-verified): row = lg*4 + j, col = ll.
    const int clocal = wc * 64 + ll;
    float watt[4];
#pragma unroll
    for (int n = 0; n < 4; ++n) watt[n] = Watt[c0 + clocal + n * 16];

#pragma unroll
    for (int m = 0; m < 4; ++m) {
#pragma unroll
        for (int j = 0; j < 4; ++j) {
            int rl = wr * 64 + m * 16 + lg * 4 + j;
            int rowg = r0 + rl;
            int b = rowg / NP;
            const float* db = dec + (size_t)b * ATT + c0;
            float s = 0.f;
#pragma unroll
            for (int n = 0; n < 4; ++n)
                s += fast_tanh(acc[m][n][j] + db[clocal + n * 16]) * watt[n];
            s += __shfl_xor(s, 1);
            s += __shfl_xor(s, 2);
            s += __shfl_xor(s, 4);
            s += __shfl_xor(s, 8);
            if (ll == 0) zred[rl * 2 + wc] = s;
        }
    }
    __syncthreads();
    if (tid < 128) {
        float t = zred[tid * 2] + zred[tid * 2 + 1];
        ztp[(size_t)nb * M_TOTAL + r0 + tid] = t;
    }
}

// ---------------------------------------------------------------------------
// K3: per-b: out = tanh(dec+stw)@Watt ; alpha = softmax(zt) ; beta.
// zt = sum of 4 N-block partials.
// ---------------------------------------------------------------------------
__global__ void k3_softmax(const float* __restrict__ dec, const float* __restrict__ stw,
                           const float* __restrict__ Watt, const float* __restrict__ ztp,
                           float* __restrict__ out, float* __restrict__ beta_ws) {
    int b = blockIdx.x;
    int t = threadIdx.x;
    __shared__ float red[256];

    float p = 0.f;
#pragma unroll
    for (int c = t; c < ATT; c += 256)
        p += fast_tanh(dec[(size_t)b * ATT + c] + stw[(size_t)b * ATT + c]) * Watt[c];
    red[t] = p;
    __syncthreads();
    for (int s = 128; s > 0; s >>= 1) { if (t < s) red[t] += red[t + s]; __syncthreads(); }
    float outv = red[0];
    __syncthreads();

    float z = -1e30f;
    if (t < NP) {
        z = ztp[b * NP + t] + ztp[M_TOTAL + b * NP + t]
          + ztp[2 * M_TOTAL + b * NP + t] + ztp[3 * M_TOTAL + b * NP + t];
    }
    red[t] = z;
    __syncthreads();
    for (int s = 128; s > 0; s >>= 1) { if (t < s) red[t] = fmaxf(red[t], red[t + s]); __syncthreads(); }
    float m1 = red[0];
    __syncthreads();

    float e = (t < NP) ? __expf(z - m1) : 0.f;
    red[t] = e;
    __syncthreads();
    for (int s = 128; s > 0; s >>= 1) { if (t < s) red[t] += red[t + s]; __syncthreads(); }
    float s1 = red[0];

    if (t < NP) out[b * NP + t] = e / s1;                       // alpha_t

    if (t == 0) {
        float m2 = fmaxf(m1, outv);
        float s2 = s1 * __expf(m1 - m2) + __expf(outv - m2);
        float beta = __expf(outv - m2) / s2;
        out[M_TOTAL + b] = beta;                                 // beta_t
        beta_ws[b] = beta;
    }
}

// ---------------------------------------------------------------------------
// K4: ct partials. grid (4 p-quarters, 256 b), block 256 (thread = 4 h).
// ---------------------------------------------------------------------------
__global__ void k4_ct(const float* __restrict__ spatial, const float* __restrict__ alpha,
                      float* __restrict__ ctp) {
    int q = blockIdx.x;
    int b = blockIdx.y;
    int t = threadIdx.x;
    __shared__ float al[49];
    if (t < 49) al[t] = alpha[b * NP + q * 49 + t];
    __syncthreads();
    const float* sp = spatial + (size_t)b * NP * HIDDEN + (size_t)q * 49 * HIDDEN + t * 4;
    float4 acc = {0.f, 0.f, 0.f, 0.f};
#pragma unroll 7
    for (int p = 0; p < 49; ++p) {
        float4 v = *(const float4*)(sp + (size_t)p * HIDDEN);
        float a = al[p];
        acc.x += a * v.x; acc.y += a * v.y; acc.z += a * v.z; acc.w += a * v.w;
    }
    *(float4*)(ctp + ((size_t)q * BATCH + b) * HIDDEN + t * 4) = acc;
}

// ---------------------------------------------------------------------------
// K5: c_hat = beta*st + (1-beta)*ct  (sums the 4 ct partials)
// ---------------------------------------------------------------------------
__global__ void k5_chat(const float* __restrict__ st, const float* __restrict__ ctp,
                        const float* __restrict__ beta, float* __restrict__ chat) {
    int g = blockIdx.x * 256 + threadIdx.x;
    int b = g >> 8;
    int h0 = (g & 255) * 4;
    float be = beta[b];
    float4 s = *(const float4*)(st + (size_t)b * HIDDEN + h0);
    float4 c = {0.f, 0.f, 0.f, 0.f};
#pragma unroll
    for (int q = 0; q < 4; ++q) {
        float4 v = *(const float4*)(ctp + ((size_t)q * BATCH + b) * HIDDEN + h0);
        c.x += v.x; c.y += v.y; c.z += v.z; c.w += v.w;
    }
    float4 o;
    o.x = be * s.x + (1.f - be) * c.x;
    o.y = be * s.y + (1.f - be) * c.y;
    o.z = be * s.z + (1.f - be) * c.z;
    o.w = be * s.w + (1.f - be) * c.w;
    *(float4*)(chat + (size_t)b * HIDDEN + h0) = o;
}

// ---------------------------------------------------------------------------
extern "C" void kernel_launch(void* const* d_in, const int* in_sizes, int n_in,
                              void* d_out, int out_size, void* d_ws, size_t ws_size,
                              hipStream_t stream) {
    const float* spatial = (const float*)d_in[0];   // (256,196,1024)
    const float* decoder = (const float*)d_in[1];   // (256,1024)
    const float* st      = (const float*)d_in[2];   // (256,1024)
    const float* Wcnn    = (const float*)d_in[3];   // (1024,512)
    const float* Wdec    = (const float*)d_in[4];   // (1024,512)
    const float* Wsen    = (const float*)d_in[5];   // (1024,512)
    const float* Watt    = (const float*)d_in[6];   // (512,1)
    float* out = (float*)d_out;   // alpha[50176] | beta[256] | c_hat[262144]

    char* ws = (char*)d_ws;
    unsigned short* Wt = (unsigned short*)(ws + 0);   // 1 MB tiled+swizzled bf16 W_cnn
    float* ztp  = (float*)(ws + 1048576);             // 4 x 50176 partials (802816 B)
    float* dec  = (float*)(ws + 1851392);             // 256x512
    float* stw  = (float*)(ws + 2375680);             // 256x512
    float* beta = (float*)(ws + 2899968);             // 256
    float* ctp  = (float*)(ws + 2901504);             // 4x256x1024 partials (4 MB)

    k0_arrange<<<256, 256, 0, stream>>>(Wcnn, Wt);
    k1_small<<<dim3(4, 32, 2), 256, 0, stream>>>(decoder, st, Wdec, Wsen, dec, stw);
    k2_fused_gemm<<<MT_TILES * NB_TILES, 256, 0, stream>>>(spatial, Wt, dec, Watt, ztp);
    k3_softmax<<<256, 256, 0, stream>>>(dec, stw, Watt, ztp, out, beta);
    k4_ct<<<dim3(4, 256), 256, 0, stream>>>(spatial, out, ctp);
    k5_chat<<<256, 256, 0, stream>>>(st, ctp, beta, out + M_TOTAL + BATCH);
}